// Round 9
// baseline (3479.307 us; speedup 1.0000x reference)
//
#include <hip/hip_runtime.h>

#define NN 30000
#define NE 480000
#define NR 16
#define D  128
#define NT 200000
#define BR 64                   // dst rows per block
#define NBLK 469                // ceil(NN/64)
#define NBINS (NBLK * NR)       // 7504
#define GS 92                   // staged edges per bin
#define PF 23                   // staged edges per wave (4 waves x 23 = 92)

// ---------------- prep kernels ----------------

__global__ void k_gather_x(const float* __restrict__ node_emb,
                           const int* __restrict__ local_nodes,
                           float* __restrict__ x) {
  int i4 = blockIdx.x * blockDim.x + threadIdx.x;
  if (i4 >= NN * (D / 4)) return;
  int n = i4 >> 5, c = i4 & 31;
  int src = local_nodes[n];
  reinterpret_cast<float4*>(x)[i4] =
      reinterpret_cast<const float4*>(node_emb)[(size_t)src * 32 + c];
}

__global__ void k_hist_bins(const int* __restrict__ ei, const int* __restrict__ et,
                            int* __restrict__ bins) {
  int e = blockIdx.x * blockDim.x + threadIdx.x;
  if (e >= NE) return;
  int d = ei[NE + e], r = et[e];
  atomicAdd(&bins[(d >> 6) * NR + r], 1);
}

__global__ void k_scan_bins(const int* __restrict__ bins, int* __restrict__ off,
                            int* __restrict__ cur) {
  __shared__ int ps[1024];
  const int t = threadIdx.x;
  const int base = t * 8;
  int c[8], s0 = 0;
#pragma unroll
  for (int u = 0; u < 8; ++u) {
    int b = base + u;
    c[u] = (b < NBINS) ? bins[b] : 0;
    s0 += c[u];
  }
  ps[t] = s0;
  __syncthreads();
  for (int dstep = 1; dstep < 1024; dstep <<= 1) {
    int v = (t >= dstep) ? ps[t - dstep] : 0;
    __syncthreads();
    ps[t] += v;
    __syncthreads();
  }
  int ex = ps[t] - s0;
#pragma unroll
  for (int u = 0; u < 8; ++u) {
    int b = base + u;
    if (b <= NBINS) {
      off[b] = ex;
      if (b < NBINS) cur[b] = ex;
    }
    ex += c[u];
  }
}

__global__ void k_fill(const int* __restrict__ ei, const int* __restrict__ et,
                       int* __restrict__ cur, int* __restrict__ srt,
                       float* __restrict__ deg) {
  int e = blockIdx.x * blockDim.x + threadIdx.x;
  if (e >= NE) return;
  int s = ei[e], d = ei[NE + e], r = et[e];
  int p = atomicAdd(&cur[(d >> 6) * NR + r], 1);
  srt[p] = ((d & 63) << 16) | s;
  atomicAdd(&deg[d], 1.0f);
}

__global__ void k_transposeW(const float* __restrict__ W0, const float* __restrict__ W1,
                             float* __restrict__ T0, float* __restrict__ T1) {
  const float* W = blockIdx.x ? W1 : W0;
  float* T = blockIdx.x ? T1 : T0;
  for (int idx = threadIdx.x; idx < D * D; idx += 256) {
    int o = idx >> 7, k = idx & 127;
    T[k * D + o] = W[idx];
  }
}

// async global->LDS, 4 B/lane
__device__ __forceinline__ void gl_lds4(const float* g, float* l) {
  __builtin_amdgcn_global_load_lds(
      (const __attribute__((address_space(1))) void*)g,
      (__attribute__((address_space(3))) void*)l, 4, 0, 0);
}

// ---------------- shared GEMM micro-tile ----------------

__device__ __forceinline__ void gemm_tile(const float (*S)[D],
                                          const float* __restrict__ Wg,
                                          int tx, int ty, float acc[8][4]) {
  const float4* __restrict__ W4 = reinterpret_cast<const float4*>(Wg);
#pragma unroll 8
  for (int k = 0; k < D; k += 4) {
    float4 a[8];
#pragma unroll
    for (int j = 0; j < 8; ++j)
      a[j] = *reinterpret_cast<const float4*>(&S[ty + 8 * j][k]);
    float4 w[4];
#pragma unroll
    for (int kk = 0; kk < 4; ++kk) w[kk] = W4[(k + kk) * 32 + tx];
#pragma unroll
    for (int kk = 0; kk < 4; ++kk) {
#pragma unroll
      for (int j = 0; j < 8; ++j) {
        float av = (kk == 0) ? a[j].x : (kk == 1) ? a[j].y
                 : (kk == 2) ? a[j].z : a[j].w;
        acc[j][0] += av * w[kk].x;
        acc[j][1] += av * w[kk].y;
        acc[j][2] += av * w[kk].z;
        acc[j][3] += av * w[kk].w;
      }
    }
  }
}

// ---------------- fused RGCN layer (unchanged round-8 algorithm) ----------------

__launch_bounds__(256, 2)
__global__ void k_fused(const float* __restrict__ x, const float* __restrict__ Wrel,
                        const float* __restrict__ WT, const float* __restrict__ Wb,
                        const int* __restrict__ srt, const int* __restrict__ off,
                        const float* __restrict__ deg, float* __restrict__ xo) {
  __shared__ float S[BR][D];
  __shared__ float G[GS][D];
  __shared__ int dls[GS];
  const int nb = blockIdx.x;
  const int row0 = nb * BR;
  const int tx = threadIdx.x & 31, ty = threadIdx.x >> 5;
  const int wave = threadIdx.x >> 6, lane = threadIdx.x & 63;
  const float2* __restrict__ x2 = reinterpret_cast<const float2*>(x);

  float acc[8][4];
#pragma unroll
  for (int j = 0; j < 8; ++j)
#pragma unroll
    for (int m = 0; m < 4; ++m) acc[j][m] = 0.f;

  auto zeroS = [&]() {
    float4* S4 = reinterpret_cast<float4*>(&S[0][0]);
#pragma unroll
    for (int t = 0; t < 8; ++t)
      S4[threadIdx.x + 256 * t] = make_float4(0.f, 0.f, 0.f, 0.f);
  };
  auto issueDMA = [&](int b) {
    const int base = off[b], end = off[b + 1];
#pragma unroll
    for (int t = 0; t < PF; ++t) {
      int s = wave + 4 * t;
      int i = base + s;
      int p = (i < end) ? srt[i] : -1;
      if (lane == 0) dls[s] = p;
      if (p >= 0) {
        const float* row = x + (size_t)(p & 0xFFFF) * D;
        gl_lds4(row + lane, &G[s][0]);
        gl_lds4(row + 64 + lane, &G[s][64]);
      }
    }
  };
  auto depositE = [&](int b) {
#pragma unroll
    for (int t = 0; t < PF; ++t) {
      int s = wave + 4 * t;
      int p = dls[s];
      if (p >= 0) {
        float2 v = *reinterpret_cast<const float2*>(&G[s][2 * lane]);
        atomicAdd(&S[p >> 16][2 * lane], v.x);
        atomicAdd(&S[p >> 16][2 * lane + 1], v.y);
      }
    }
    const int end = off[b + 1];
    for (int i = off[b] + GS + wave; i < end; i += 4) {
      int p = srt[i];
      float2 vv = x2[(size_t)(p & 0xFFFF) * 64 + lane];
      atomicAdd(&S[p >> 16][2 * lane], vv.x);
      atomicAdd(&S[p >> 16][2 * lane + 1], vv.y);
    }
  };

  zeroS();
  issueDMA(nb * NR);
  __syncthreads();

  for (int r = 0; r < NR; ++r) {
    depositE(nb * NR + r);
    __syncthreads();
    if (r + 1 < NR) issueDMA(nb * NR + r + 1);
    gemm_tile(S, Wrel + (size_t)r * D * D, tx, ty, acc);
    __syncthreads();
    if (r + 1 < NR) {
      zeroS();
      __syncthreads();
    }
  }

#pragma unroll
  for (int j = 0; j < 8; ++j) {
    int row = row0 + ty + 8 * j;
    float dv = (row < NN) ? deg[row] : 1.f;
    float inv = 1.f / fmaxf(dv, 1.f);
#pragma unroll
    for (int m = 0; m < 4; ++m) acc[j][m] *= inv;
  }

#pragma unroll
  for (int t = 0; t < 8; ++t) {
    int idx = threadIdx.x + 256 * t;
    int rw = idx >> 5, c = idx & 31;
    float4 vv = make_float4(0.f, 0.f, 0.f, 0.f);
    if (row0 + rw < NN)
      vv = reinterpret_cast<const float4*>(x)[(size_t)(row0 + rw) * 32 + c];
    *reinterpret_cast<float4*>(&S[rw][4 * c]) = vv;
  }
  __syncthreads();
  gemm_tile(S, WT, tx, ty, acc);

  const float4 bb = reinterpret_cast<const float4*>(Wb)[tx];
#pragma unroll
  for (int j = 0; j < 8; ++j) {
    int row = row0 + ty + 8 * j;
    if (row < NN) {
      float4 o;
      o.x = fmaxf(acc[j][0] + bb.x, 0.f);
      o.y = fmaxf(acc[j][1] + bb.y, 0.f);
      o.z = fmaxf(acc[j][2] + bb.z, 0.f);
      o.w = fmaxf(acc[j][3] + bb.w, 0.f);
      reinterpret_cast<float4*>(xo + (size_t)row * D)[tx] = o;
    }
  }
}

// ---------------- ablation kernels (diagnostic; output to dead buffer) ----------
// All keep the same 80 KB LDS footprint (S+G+dls) to pin occupancy at 2 blocks/CU.

#define ABL_PROLOG                                                       \
  __shared__ float S[BR][D];                                             \
  __shared__ float G[GS][D];                                             \
  __shared__ int dls[GS];                                                \
  const int nb = blockIdx.x;                                             \
  const int row0 = nb * BR;                                              \
  const int tx = threadIdx.x & 31, ty = threadIdx.x >> 5;                \
  if (threadIdx.x == 0) { dls[0] = nb; G[0][0] = (float)nb; }            \
  float acc[8][4];                                                       \
  _Pragma("unroll") for (int j = 0; j < 8; ++j)                          \
    _Pragma("unroll") for (int m = 0; m < 4; ++m) acc[j][m] = 0.f;

#define ABL_STAGE_S                                                      \
  _Pragma("unroll") for (int t = 0; t < 8; ++t) {                        \
    int idx = threadIdx.x + 256 * t;                                     \
    int rw = idx >> 5, c = idx & 31;                                     \
    float4 vv = make_float4(0.f, 0.f, 0.f, 0.f);                         \
    if (row0 + rw < NN)                                                  \
      vv = reinterpret_cast<const float4*>(x)[(size_t)(row0 + rw) * 32 + c]; \
    *reinterpret_cast<float4*>(&S[rw][4 * c]) = vv;                      \
  }                                                                      \
  __syncthreads();

#define ABL_EPILOG                                                       \
  const float4 bb = reinterpret_cast<const float4*>(Wb)[tx];             \
  _Pragma("unroll") for (int j = 0; j < 8; ++j) {                        \
    int row = row0 + ty + 8 * j;                                         \
    if (row < NN) {                                                      \
      float dv = deg[row];                                               \
      float inv = 1.f / fmaxf(dv, 1.f);                                  \
      float4 o;                                                          \
      o.x = fmaxf(acc[j][0] * inv + bb.x, 0.f);                          \
      o.y = fmaxf(acc[j][1] * inv + bb.y, 0.f);                          \
      o.z = fmaxf(acc[j][2] * inv + bb.z, 0.f);                          \
      o.w = fmaxf(acc[j][3] * inv + bb.w, 0.f);                          \
      reinterpret_cast<float4*>(xo + (size_t)row * D)[tx] = o;           \
    }                                                                    \
  }

// GEMM + barrier skeleton only (no edge work)
__launch_bounds__(256, 2)
__global__ void abl_gemm(const float* __restrict__ x, const float* __restrict__ Wrel,
                         const float* __restrict__ WT, const float* __restrict__ Wb,
                         const float* __restrict__ deg, float* __restrict__ xo) {
  ABL_PROLOG
  ABL_STAGE_S
  for (int r = 0; r < NR; ++r) {
    gemm_tile(S, Wrel + (size_t)r * D * D, tx, ty, acc);
    __syncthreads(); __syncthreads(); __syncthreads();
  }
  gemm_tile(S, WT, tx, ty, acc);
  ABL_EPILOG
}

// same, but VGPR cap relaxed (tests compiler load-pipelining headroom)
__launch_bounds__(256, 1)
__global__ void abl_gemm_hi(const float* __restrict__ x, const float* __restrict__ Wrel,
                            const float* __restrict__ WT, const float* __restrict__ Wb,
                            const float* __restrict__ deg, float* __restrict__ xo) {
  ABL_PROLOG
  ABL_STAGE_S
  for (int r = 0; r < NR; ++r) {
    gemm_tile(S, Wrel + (size_t)r * D * D, tx, ty, acc);
    __syncthreads(); __syncthreads(); __syncthreads();
  }
  gemm_tile(S, WT, tx, ty, acc);
  ABL_EPILOG
}

// GEMM with A-operand register-resident (no LDS reads in k-loop)
__launch_bounds__(256, 2)
__global__ void abl_gemm_reg(const float* __restrict__ x, const float* __restrict__ Wrel,
                             const float* __restrict__ WT, const float* __restrict__ Wb,
                             const float* __restrict__ deg, float* __restrict__ xo) {
  ABL_PROLOG
  ABL_STAGE_S
  float4 a[8];
#pragma unroll
  for (int j = 0; j < 8; ++j)
    a[j] = *reinterpret_cast<const float4*>(&S[ty + 8 * j][4 * (tx & 31) % D]);
  for (int r = 0; r < NR + 1; ++r) {
    const float* Wg = (r < NR) ? (Wrel + (size_t)r * D * D) : WT;
    const float4* __restrict__ W4 = reinterpret_cast<const float4*>(Wg);
#pragma unroll 8
    for (int k = 0; k < D; k += 4) {
      float4 w[4];
#pragma unroll
      for (int kk = 0; kk < 4; ++kk) w[kk] = W4[(k + kk) * 32 + tx];
#pragma unroll
      for (int kk = 0; kk < 4; ++kk) {
#pragma unroll
        for (int j = 0; j < 8; ++j) {
          float av = (kk == 0) ? a[j].x : (kk == 1) ? a[j].y
                   : (kk == 2) ? a[j].z : a[j].w;
          acc[j][0] += av * w[kk].x;
          acc[j][1] += av * w[kk].y;
          acc[j][2] += av * w[kk].z;
          acc[j][3] += av * w[kk].w;
        }
      }
    }
    __syncthreads(); __syncthreads(); __syncthreads();
  }
  ABL_EPILOG
}

// edge pipeline only (gather/deposit/zero + barriers; GEMM stubbed to 1 LDS read)
__launch_bounds__(256, 2)
__global__ void abl_edges(const float* __restrict__ x, const float* __restrict__ Wb,
                          const int* __restrict__ srt, const int* __restrict__ off,
                          const float* __restrict__ deg, float* __restrict__ xo) {
  ABL_PROLOG
  const int wave = threadIdx.x >> 6, lane = threadIdx.x & 63;
  const float2* __restrict__ x2 = reinterpret_cast<const float2*>(x);
  auto zeroS = [&]() {
    float4* S4 = reinterpret_cast<float4*>(&S[0][0]);
#pragma unroll
    for (int t = 0; t < 8; ++t)
      S4[threadIdx.x + 256 * t] = make_float4(0.f, 0.f, 0.f, 0.f);
  };
  auto issueDMA = [&](int b) {
    const int base = off[b], end = off[b + 1];
#pragma unroll
    for (int t = 0; t < PF; ++t) {
      int s = wave + 4 * t;
      int i = base + s;
      int p = (i < end) ? srt[i] : -1;
      if (lane == 0) dls[s] = p;
      if (p >= 0) {
        const float* row = x + (size_t)(p & 0xFFFF) * D;
        gl_lds4(row + lane, &G[s][0]);
        gl_lds4(row + 64 + lane, &G[s][64]);
      }
    }
  };
  auto depositE = [&](int b) {
#pragma unroll
    for (int t = 0; t < PF; ++t) {
      int s = wave + 4 * t;
      int p = dls[s];
      if (p >= 0) {
        float2 v = *reinterpret_cast<const float2*>(&G[s][2 * lane]);
        atomicAdd(&S[p >> 16][2 * lane], v.x);
        atomicAdd(&S[p >> 16][2 * lane + 1], v.y);
      }
    }
    const int end = off[b + 1];
    for (int i = off[b] + GS + wave; i < end; i += 4) {
      int p = srt[i];
      float2 vv = x2[(size_t)(p & 0xFFFF) * 64 + lane];
      atomicAdd(&S[p >> 16][2 * lane], vv.x);
      atomicAdd(&S[p >> 16][2 * lane + 1], vv.y);
    }
  };

  zeroS();
  issueDMA(nb * NR);
  __syncthreads();
  for (int r = 0; r < NR; ++r) {
    depositE(nb * NR + r);
    __syncthreads();
    if (r + 1 < NR) issueDMA(nb * NR + r + 1);
    {  // GEMM stub: keep S live, negligible cost
      float4 sv = *reinterpret_cast<const float4*>(&S[(ty + 2 * r) & 63][4 * tx]);
      acc[0][0] += sv.x; acc[0][1] += sv.y;
      acc[0][2] += sv.z; acc[0][3] += sv.w;
    }
    __syncthreads();
    if (r + 1 < NR) {
      zeroS();
      __syncthreads();
    }
  }
  ABL_EPILOG
}

// ---------------- DistMult scoring ----------------

__global__ void k_score(const float* __restrict__ x, const float* __restrict__ rel,
                        const int* __restrict__ hh, const int* __restrict__ rr,
                        const int* __restrict__ tt, float* __restrict__ out) {
  int gw = (blockIdx.x * blockDim.x + threadIdx.x) >> 6;
  int lane = threadIdx.x & 63;
  int nw = (gridDim.x * blockDim.x) >> 6;
  for (int i = gw; i < NT; i += nw) {
    const float2* ph = reinterpret_cast<const float2*>(x + (size_t)hh[i] * D);
    const float2* pr = reinterpret_cast<const float2*>(rel + (size_t)rr[i] * D);
    const float2* pt = reinterpret_cast<const float2*>(x + (size_t)tt[i] * D);
    float2 a = ph[lane], b = pr[lane], c = pt[lane];
    float v = a.x * b.x * c.x + a.y * b.y * c.y;
#pragma unroll
    for (int m = 32; m; m >>= 1) v += __shfl_xor(v, m);
    if (lane == 0) out[i] = v;
  }
}

// ---------------- launch ----------------

extern "C" void kernel_launch(void* const* d_in, const int* in_sizes, int n_in,
                              void* d_out, int out_size, void* d_ws, size_t ws_size,
                              hipStream_t stream) {
  const float* node_emb = (const float*)d_in[0];
  const float* rel_emb  = (const float*)d_in[1];
  const float* W_rel0   = (const float*)d_in[2];
  const float* Wself_w0 = (const float*)d_in[3];
  const float* Wself_b0 = (const float*)d_in[4];
  const float* W_rel1   = (const float*)d_in[5];
  const float* Wself_w1 = (const float*)d_in[6];
  const float* Wself_b1 = (const float*)d_in[7];
  const int* local_nodes = (const int*)d_in[8];
  const int* edge_index  = (const int*)d_in[9];
  const int* edge_type   = (const int*)d_in[10];
  const int* h_loc = (const int*)d_in[11];
  const int* r_ids = (const int*)d_in[12];
  const int* t_loc = (const int*)d_in[13];
  float* out = (float*)d_out;

  char* ws = (char*)d_ws;
  float* x_a = (float*)(ws + 0);
  float* x_b = (float*)(ws + 15360000);
  float* WT0 = (float*)(ws + 30720000);
  float* WT1 = (float*)(ws + 30785536);
  float* deg = (float*)(ws + 30851072);
  int* bins  = (int*)(ws + 30971072);
  int* off   = (int*)(ws + 31001088);
  int* cur   = (int*)(ws + 31031108);
  int* srt   = (int*)(ws + 31061124);
  if (ws_size < (size_t)32981124) return;

  hipMemsetAsync(ws + 30851072, 0, 150016, stream);

  k_gather_x<<<3750, 256, 0, stream>>>(node_emb, local_nodes, x_a);
  k_hist_bins<<<1875, 256, 0, stream>>>(edge_index, edge_type, bins);
  k_scan_bins<<<1, 1024, 0, stream>>>(bins, off, cur);
  k_fill<<<1875, 256, 0, stream>>>(edge_index, edge_type, cur, srt, deg);
  k_transposeW<<<2, 256, 0, stream>>>(Wself_w0, Wself_w1, WT0, WT1);

  k_fused<<<NBLK, 256, 0, stream>>>(x_a, W_rel0, WT0, Wself_b0, srt, off, deg, x_b);
  k_fused<<<NBLK, 256, 0, stream>>>(x_b, W_rel1, WT1, Wself_b1, srt, off, deg, x_a);

  k_score<<<1024, 256, 0, stream>>>(x_a, rel_emb, h_loc, r_ids, t_loc, out);

  // ---- diagnostic ablations (outputs to dead x_b; rocprof times each) ----
  k_fused<<<NBLK, 256, 0, stream>>>(x_a, W_rel0, WT0, Wself_b0, srt, off, deg, x_b);
  abl_gemm<<<NBLK, 256, 0, stream>>>(x_a, W_rel0, WT0, Wself_b0, deg, x_b);
  abl_gemm_hi<<<NBLK, 256, 0, stream>>>(x_a, W_rel0, WT0, Wself_b0, deg, x_b);
  abl_gemm_reg<<<NBLK, 256, 0, stream>>>(x_a, W_rel0, WT0, Wself_b0, deg, x_b);
  abl_edges<<<NBLK, 256, 0, stream>>>(x_a, Wself_b0, srt, off, deg, x_b);
}

// Round 10
// 1346.465 us; speedup vs baseline: 2.5840x; 2.5840x over previous
//
#include <hip/hip_runtime.h>

#define NN 30000
#define NE 480000
#define NR 16
#define D  128
#define NT 200000
#define BR 64                   // dst rows per block
#define NBLK 469                // ceil(NN/64)
#define NBINS (NBLK * NR)       // 7504
#define GS 92                   // staged edges per bin
#define PF 23                   // staged edges per wave (4 waves x 23 = 92)

typedef short bf16x8 __attribute__((ext_vector_type(8)));
typedef float f32x4 __attribute__((ext_vector_type(4)));

__device__ __forceinline__ unsigned short f2bf(float f) {
  unsigned u = __float_as_uint(f);
  return (unsigned short)((u + 0x7FFF + ((u >> 16) & 1)) >> 16);   // RNE
}
__device__ __forceinline__ float bf2f(unsigned short h) {
  return __uint_as_float(((unsigned)h) << 16);
}

// ---------------- prep kernels ----------------

__global__ void k_gather_x(const float* __restrict__ node_emb,
                           const int* __restrict__ local_nodes,
                           float* __restrict__ x) {
  int i4 = blockIdx.x * blockDim.x + threadIdx.x;
  if (i4 >= NN * (D / 4)) return;
  int n = i4 >> 5, c = i4 & 31;
  int src = local_nodes[n];
  reinterpret_cast<float4*>(x)[i4] =
      reinterpret_cast<const float4*>(node_emb)[(size_t)src * 32 + c];
}

__global__ void k_hist_bins(const int* __restrict__ ei, const int* __restrict__ et,
                            int* __restrict__ bins) {
  int e = blockIdx.x * blockDim.x + threadIdx.x;
  if (e >= NE) return;
  int d = ei[NE + e], r = et[e];
  atomicAdd(&bins[(d >> 6) * NR + r], 1);
}

__global__ void k_scan_bins(const int* __restrict__ bins, int* __restrict__ off,
                            int* __restrict__ cur) {
  __shared__ int ps[1024];
  const int t = threadIdx.x;
  const int base = t * 8;
  int c[8], s0 = 0;
#pragma unroll
  for (int u = 0; u < 8; ++u) {
    int b = base + u;
    c[u] = (b < NBINS) ? bins[b] : 0;
    s0 += c[u];
  }
  ps[t] = s0;
  __syncthreads();
  for (int dstep = 1; dstep < 1024; dstep <<= 1) {
    int v = (t >= dstep) ? ps[t - dstep] : 0;
    __syncthreads();
    ps[t] += v;
    __syncthreads();
  }
  int ex = ps[t] - s0;
#pragma unroll
  for (int u = 0; u < 8; ++u) {
    int b = base + u;
    if (b <= NBINS) {
      off[b] = ex;
      if (b < NBINS) cur[b] = ex;
    }
    ex += c[u];
  }
}

__global__ void k_fill(const int* __restrict__ ei, const int* __restrict__ et,
                       int* __restrict__ cur, int* __restrict__ srt,
                       float* __restrict__ deg) {
  int e = blockIdx.x * blockDim.x + threadIdx.x;
  if (e >= NE) return;
  int s = ei[e], d = ei[NE + e], r = et[e];
  int p = atomicAdd(&cur[(d >> 6) * NR + r], 1);
  srt[p] = ((d & 63) << 16) | s;
  atomicAdd(&deg[d], 1.0f);
}

// Pack W into MFMA-fragment-ordered bf16 hi/lo.
// Fragment layout (mfma_f32_16x16x32_bf16, HW-verified tr-read mapping):
//   lane l, elem e:  k = kt*32 + (e>>2)*16 + (l>>4)*4 + (e&3),  n = nt*16 + (l&15)
// Storage: bf16 unit idx = (((rel*4+kt)*8+nt)*2+half)*512 + l*8 + e
__global__ void k_packW(const float* __restrict__ Wr, const float* __restrict__ Ws,
                        unsigned short* __restrict__ out) {
  const int r = blockIdx.x;           // 0..15 relations, 16 = self (transposed)
  for (int i = threadIdx.x; i < 16384; i += 256) {
    int e = i & 7, l = (i >> 3) & 63, nt = (i >> 9) & 7, kt = i >> 12;
    int k = kt * 32 + ((e >> 2) << 4) + (((l >> 4) & 3) << 2) + (e & 3);
    int n = nt * 16 + (l & 15);
    float w = (r < 16) ? Wr[((size_t)r << 14) + (k << 7) + n]
                       : Ws[(n << 7) + k];          // self: B[k][n] = Wself[n][k]
    unsigned short h = f2bf(w);
    unsigned short lo = f2bf(w - bf2f(h));
    size_t base = ((((size_t)r * 4 + kt) * 8 + nt) * 2) * 512 + (size_t)l * 8 + e;
    out[base] = h;                    // half 0 (hi)
    out[base + 512] = lo;             // half 1 (lo)
  }
}

// async global->LDS, 4 B/lane
__device__ __forceinline__ void gl_lds4(const float* g, float* l) {
  __builtin_amdgcn_global_load_lds(
      (const __attribute__((address_space(1))) void*)g,
      (__attribute__((address_space(3))) void*)l, 4, 0, 0);
}

// ---------------- MFMA tile: acc[nt] += S_tile(mtile=wave) @ W_rel ----------------
// S is col-swizzled at float4 granularity: physical_f4 = logical_f4 ^ ((row&7)<<2).

#define CVT1(e, val) { unsigned short h_ = f2bf(val); ah[e] = (short)h_; \
                       al[e] = (short)f2bf((val) - bf2f(h_)); }

__device__ __forceinline__ void mfma_rel(const float (*S)[D],
                                         const bf16x8* __restrict__ Wf,
                                         int lane, int wave, f32x4 acc[8]) {
  const int m = lane & 15, kg = lane >> 4;
  const int row = wave * 16 + m;
  const int sw = (row & 7) << 2;
#pragma unroll
  for (int kt = 0; kt < 4; ++kt) {
    float4 v0 = *reinterpret_cast<const float4*>(&S[row][((kt * 8 + kg) ^ sw) << 2]);
    float4 v1 = *reinterpret_cast<const float4*>(&S[row][((kt * 8 + 4 + kg) ^ sw) << 2]);
    bf16x8 ah, al;
    CVT1(0, v0.x) CVT1(1, v0.y) CVT1(2, v0.z) CVT1(3, v0.w)
    CVT1(4, v1.x) CVT1(5, v1.y) CVT1(6, v1.z) CVT1(7, v1.w)
    const bf16x8* Wk = Wf + (size_t)kt * 1024 + lane;
#pragma unroll
    for (int nt = 0; nt < 8; ++nt) {
      bf16x8 bh = Wk[nt * 128];
      bf16x8 bl = Wk[nt * 128 + 64];
      acc[nt] = __builtin_amdgcn_mfma_f32_16x16x32_bf16(ah, bh, acc[nt], 0, 0, 0);
      acc[nt] = __builtin_amdgcn_mfma_f32_16x16x32_bf16(al, bh, acc[nt], 0, 0, 0);
      acc[nt] = __builtin_amdgcn_mfma_f32_16x16x32_bf16(ah, bl, acc[nt], 0, 0, 0);
    }
  }
}

// ---------------- fused RGCN layer ----------------

__launch_bounds__(256, 2)
__global__ void k_fused(const float* __restrict__ x,
                        const unsigned short* __restrict__ Wpk,
                        const float* __restrict__ Wb,
                        const int* __restrict__ srt, const int* __restrict__ off,
                        const float* __restrict__ deg, float* __restrict__ xo) {
  __shared__ float S[BR][D];             // 32,768 B (swizzled accumulation tile)
  __shared__ float G[GS][D];             // 47,104 B DMA staging
  __shared__ int dls[GS];
  const int nb = blockIdx.x;
  const int row0 = nb * BR;
  const int wave = threadIdx.x >> 6, lane = threadIdx.x & 63;
  const float2* __restrict__ x2 = reinterpret_cast<const float2*>(x);
  const bf16x8* __restrict__ Wf = reinterpret_cast<const bf16x8*>(Wpk);

  f32x4 acc[8];
#pragma unroll
  for (int nt = 0; nt < 8; ++nt) acc[nt] = 0.f;

  auto zeroS = [&]() {
    float4* S4 = reinterpret_cast<float4*>(&S[0][0]);
#pragma unroll
    for (int t = 0; t < 8; ++t)
      S4[threadIdx.x + 256 * t] = make_float4(0.f, 0.f, 0.f, 0.f);
  };
  auto issueDMA = [&](int b) {
    const int base = off[b], end = off[b + 1];
#pragma unroll
    for (int t = 0; t < PF; ++t) {
      int s = wave + 4 * t;
      int i = base + s;
      int p = (i < end) ? srt[i] : -1;
      if (lane == 0) dls[s] = p;
      if (p >= 0) {
        const float* row = x + (size_t)(p & 0xFFFF) * D;
        gl_lds4(row + lane, &G[s][0]);
        gl_lds4(row + 64 + lane, &G[s][64]);
      }
    }
  };
  auto depositE = [&](int b) {
#pragma unroll
    for (int t = 0; t < PF; ++t) {
      int s = wave + 4 * t;
      int p = dls[s];
      if (p >= 0) {
        float2 v = *reinterpret_cast<const float2*>(&G[s][2 * lane]);
        int dl = p >> 16;
        float* dst = &S[dl][(((lane >> 1) ^ ((dl & 7) << 2)) << 2) + ((lane & 1) << 1)];
        atomicAdd(dst, v.x);
        atomicAdd(dst + 1, v.y);
      }
    }
    const int end = off[b + 1];            // overflow edges (bin > GS), rare
    for (int i = off[b] + GS + wave; i < end; i += 4) {
      int p = srt[i];
      float2 vv = x2[(size_t)(p & 0xFFFF) * 64 + lane];
      int dl = p >> 16;
      float* dst = &S[dl][(((lane >> 1) ^ ((dl & 7) << 2)) << 2) + ((lane & 1) << 1)];
      atomicAdd(dst, vv.x);
      atomicAdd(dst + 1, vv.y);
    }
  };

  zeroS();
  issueDMA(nb * NR);
  __syncthreads();                         // zero + dls visible, DMA drained

  for (int r = 0; r < NR; ++r) {
    depositE(nb * NR + r);                 // LDS-only
    __syncthreads();                       // S complete for relation r
    if (r + 1 < NR) issueDMA(nb * NR + r + 1);
    mfma_rel(S, Wf + (size_t)r * 4096, lane, wave, acc);
    __syncthreads();                       // S reads done; DMAs drained
    if (r + 1 < NR) {
      zeroS();
      __syncthreads();
    }
  }

  // scale message aggregate by 1/deg (C rows: (lane>>4)*4 + j within mtile=wave)
  const int kg = lane >> 4;
#pragma unroll
  for (int j = 0; j < 4; ++j) {
    int row = row0 + wave * 16 + kg * 4 + j;
    float dv = (row < NN) ? deg[row] : 1.f;
    float inv = 1.f / fmaxf(dv, 1.f);
#pragma unroll
    for (int nt = 0; nt < 8; ++nt) acc[nt][j] *= inv;
  }

  // self phase: stage x rows into S (swizzled, full overwrite), then rel-16 MFMA
#pragma unroll
  for (int t = 0; t < 8; ++t) {
    int idx = threadIdx.x + 256 * t;
    int rw = idx >> 5, c = idx & 31;
    float4 vv = make_float4(0.f, 0.f, 0.f, 0.f);
    if (row0 + rw < NN)
      vv = reinterpret_cast<const float4*>(x)[(size_t)(row0 + rw) * 32 + c];
    *reinterpret_cast<float4*>(&S[rw][(c ^ ((rw & 7) << 2)) << 2]) = vv;
  }
  __syncthreads();
  mfma_rel(S, Wf + (size_t)16 * 4096, lane, wave, acc);

  // epilogue: relu(acc + bias); C layout col = lane&15 + nt*16, row = kg*4+j
#pragma unroll
  for (int nt = 0; nt < 8; ++nt) {
    int col = nt * 16 + (lane & 15);
    float b = Wb[col];
#pragma unroll
    for (int j = 0; j < 4; ++j) {
      int row = row0 + wave * 16 + kg * 4 + j;
      if (row < NN)
        xo[(size_t)row * D + col] = fmaxf(acc[nt][j] + b, 0.f);
    }
  }
}

// ---------------- DistMult scoring ----------------

__global__ void k_score(const float* __restrict__ x, const float* __restrict__ rel,
                        const int* __restrict__ hh, const int* __restrict__ rr,
                        const int* __restrict__ tt, float* __restrict__ out) {
  int gw = (blockIdx.x * blockDim.x + threadIdx.x) >> 6;
  int lane = threadIdx.x & 63;
  int nw = (gridDim.x * blockDim.x) >> 6;
  for (int i = gw; i < NT; i += nw) {
    const float2* ph = reinterpret_cast<const float2*>(x + (size_t)hh[i] * D);
    const float2* pr = reinterpret_cast<const float2*>(rel + (size_t)rr[i] * D);
    const float2* pt = reinterpret_cast<const float2*>(x + (size_t)tt[i] * D);
    float2 a = ph[lane], b = pr[lane], c = pt[lane];
    float v = a.x * b.x * c.x + a.y * b.y * c.y;
#pragma unroll
    for (int m = 32; m; m >>= 1) v += __shfl_xor(v, m);
    if (lane == 0) out[i] = v;
  }
}

// ---------------- launch ----------------

extern "C" void kernel_launch(void* const* d_in, const int* in_sizes, int n_in,
                              void* d_out, int out_size, void* d_ws, size_t ws_size,
                              hipStream_t stream) {
  const float* node_emb = (const float*)d_in[0];
  const float* rel_emb  = (const float*)d_in[1];
  const float* W_rel0   = (const float*)d_in[2];
  const float* Wself_w0 = (const float*)d_in[3];
  const float* Wself_b0 = (const float*)d_in[4];
  const float* W_rel1   = (const float*)d_in[5];
  const float* Wself_w1 = (const float*)d_in[6];
  const float* Wself_b1 = (const float*)d_in[7];
  const int* local_nodes = (const int*)d_in[8];
  const int* edge_index  = (const int*)d_in[9];
  const int* edge_type   = (const int*)d_in[10];
  const int* h_loc = (const int*)d_in[11];
  const int* r_ids = (const int*)d_in[12];
  const int* t_loc = (const int*)d_in[13];
  float* out = (float*)d_out;

  // workspace layout (bytes)
  char* ws = (char*)d_ws;
  float* x_a = (float*)(ws + 0);                    // 15,360,000
  float* x_b = (float*)(ws + 15360000);             // 15,360,000
  float* deg = (float*)(ws + 30720000);             //    120,000
  int* bins  = (int*)(ws + 30840000);               //     30,016
  int* off   = (int*)(ws + 30870016);               //     30,020 (7505 ints)
  int* cur   = (int*)(ws + 30900036);               //     30,016
  int* srt   = (int*)(ws + 30930052);               //  1,920,000
  unsigned short* Wpk0 = (unsigned short*)(ws + 32850064);   // 1,114,112 (16B-aligned)
  unsigned short* Wpk1 = (unsigned short*)(ws + 33964176);   // 1,114,112
  if (ws_size < (size_t)35078288) return;

  // zero deg + bins (contiguous); off/cur/srt/Wpk fully overwritten downstream
  hipMemsetAsync(ws + 30720000, 0, 150016, stream);

  k_gather_x<<<3750, 256, 0, stream>>>(node_emb, local_nodes, x_a);
  k_hist_bins<<<1875, 256, 0, stream>>>(edge_index, edge_type, bins);
  k_scan_bins<<<1, 1024, 0, stream>>>(bins, off, cur);
  k_fill<<<1875, 256, 0, stream>>>(edge_index, edge_type, cur, srt, deg);
  k_packW<<<17, 256, 0, stream>>>(W_rel0, Wself_w0, Wpk0);
  k_packW<<<17, 256, 0, stream>>>(W_rel1, Wself_w1, Wpk1);

  k_fused<<<NBLK, 256, 0, stream>>>(x_a, Wpk0, Wself_b0, srt, off, deg, x_b);
  k_fused<<<NBLK, 256, 0, stream>>>(x_b, Wpk1, Wself_b1, srt, off, deg, x_a);

  k_score<<<1024, 256, 0, stream>>>(x_a, rel_emb, h_loc, r_ids, t_loc, out);
}

// Round 15
// 1337.743 us; speedup vs baseline: 2.6009x; 1.0065x over previous
//
#include <hip/hip_runtime.h>

#define NN 30000
#define NE 480000
#define NR 16
#define D  128
#define NT 200000
#define BR 64                   // dst rows per block
#define NBLK 469                // ceil(NN/64)
#define NBINS (NBLK * NR)       // 7504
#define GS 92                   // staged edges per bin
#define PF 23                   // staged edges per wave (4 waves x 23 = 92)

typedef short bf16x8 __attribute__((ext_vector_type(8)));
typedef float f32x4 __attribute__((ext_vector_type(4)));

__device__ __forceinline__ unsigned short f2bf(float f) {
  unsigned u = __float_as_uint(f);
  return (unsigned short)((u + 0x7FFF + ((u >> 16) & 1)) >> 16);   // RNE
}
__device__ __forceinline__ float bf2f(unsigned short h) {
  return __uint_as_float(((unsigned)h) << 16);
}

// ---------------- prep kernels ----------------

__global__ void k_gather_x(const float* __restrict__ node_emb,
                           const int* __restrict__ local_nodes,
                           float* __restrict__ x) {
  int i4 = blockIdx.x * blockDim.x + threadIdx.x;
  if (i4 >= NN * (D / 4)) return;
  int n = i4 >> 5, c = i4 & 31;
  int src = local_nodes[n];
  reinterpret_cast<float4*>(x)[i4] =
      reinterpret_cast<const float4*>(node_emb)[(size_t)src * 32 + c];
}

__global__ void k_hist_bins(const int* __restrict__ ei, const int* __restrict__ et,
                            int* __restrict__ bins) {
  int e = blockIdx.x * blockDim.x + threadIdx.x;
  if (e >= NE) return;
  int d = ei[NE + e], r = et[e];
  atomicAdd(&bins[(d >> 6) * NR + r], 1);
}

__global__ void k_scan_bins(const int* __restrict__ bins, int* __restrict__ off,
                            int* __restrict__ cur) {
  __shared__ int ps[1024];
  const int t = threadIdx.x;
  const int base = t * 8;
  int c[8], s0 = 0;
#pragma unroll
  for (int u = 0; u < 8; ++u) {
    int b = base + u;
    c[u] = (b < NBINS) ? bins[b] : 0;
    s0 += c[u];
  }
  ps[t] = s0;
  __syncthreads();
  for (int dstep = 1; dstep < 1024; dstep <<= 1) {
    int v = (t >= dstep) ? ps[t - dstep] : 0;
    __syncthreads();
    ps[t] += v;
    __syncthreads();
  }
  int ex = ps[t] - s0;
#pragma unroll
  for (int u = 0; u < 8; ++u) {
    int b = base + u;
    if (b <= NBINS) {
      off[b] = ex;
      if (b < NBINS) cur[b] = ex;
    }
    ex += c[u];
  }
}

__global__ void k_fill(const int* __restrict__ ei, const int* __restrict__ et,
                       int* __restrict__ cur, int* __restrict__ srt,
                       float* __restrict__ deg) {
  int e = blockIdx.x * blockDim.x + threadIdx.x;
  if (e >= NE) return;
  int s = ei[e], d = ei[NE + e], r = et[e];
  int p = atomicAdd(&cur[(d >> 6) * NR + r], 1);
  srt[p] = ((d & 63) << 16) | s;
  atomicAdd(&deg[d], 1.0f);
}

// Pack W into MFMA-fragment-ordered bf16 hi/lo.
// Fragment layout (mfma_f32_16x16x32_bf16):
//   lane l, elem e:  k = kt*32 + (e>>2)*16 + (l>>4)*4 + (e&3),  n = nt*16 + (l&15)
// Storage: bf16 unit idx = (((rel*4+kt)*8+nt)*2+half)*512 + l*8 + e
__global__ void k_packW(const float* __restrict__ Wr, const float* __restrict__ Ws,
                        unsigned short* __restrict__ out) {
  const int r = blockIdx.x;           // 0..15 relations, 16 = self (transposed)
  for (int i = threadIdx.x; i < 16384; i += 256) {
    int e = i & 7, l = (i >> 3) & 63, nt = (i >> 9) & 7, kt = i >> 12;
    int k = kt * 32 + ((e >> 2) << 4) + (((l >> 4) & 3) << 2) + (e & 3);
    int n = nt * 16 + (l & 15);
    float w = (r < 16) ? Wr[((size_t)r << 14) + (k << 7) + n]
                       : Ws[(n << 7) + k];          // self: B[k][n] = Wself[n][k]
    unsigned short h = f2bf(w);
    unsigned short lo = f2bf(w - bf2f(h));
    size_t base = ((((size_t)r * 4 + kt) * 8 + nt) * 2) * 512 + (size_t)l * 8 + e;
    out[base] = h;                    // half 0 (hi)
    out[base + 512] = lo;             // half 1 (lo)
  }
}

// async global->LDS, 4 B/lane
__device__ __forceinline__ void gl_lds4(const float* g, float* l) {
  __builtin_amdgcn_global_load_lds(
      (const __attribute__((address_space(1))) void*)g,
      (__attribute__((address_space(3))) void*)l, 4, 0, 0);
}

// ---------------- MFMA tile: acc[nt] += S_tile(mtile=wave) @ W_rel ----------------
// S col-swizzle at float4 granularity, LOW bits: physical_f4 = logical_f4 ^ (row&7).

#define CVT1(e, val) { unsigned short h_ = f2bf(val); ah[e] = (short)h_; \
                       al[e] = (short)f2bf((val) - bf2f(h_)); }

__device__ __forceinline__ void mfma_rel(const float (*S)[D],
                                         const bf16x8* __restrict__ Wf,
                                         int lane, int wave, f32x4 acc[8]) {
  const int m = lane & 15, kg = lane >> 4;
  const int row = wave * 16 + m;
  const int sw = row & 7;
#pragma unroll
  for (int kt = 0; kt < 4; ++kt) {
    // batch all W fragments for this kt first: 16 back-to-back dwordx4 loads
    // (memory-level parallelism; L2 latency amortized across 16 in-flight loads)
    const bf16x8* Wk = Wf + (size_t)kt * 1024 + lane;
    bf16x8 bh[8], bl[8];
#pragma unroll
    for (int nt = 0; nt < 8; ++nt) {
      bh[nt] = Wk[nt * 128];
      bl[nt] = Wk[nt * 128 + 64];
    }
    // S reads (swizzled) + conversions overlap the W-load latency
    float4 v0 = *reinterpret_cast<const float4*>(&S[row][((kt * 8 + kg) ^ sw) << 2]);
    float4 v1 = *reinterpret_cast<const float4*>(&S[row][((kt * 8 + 4 + kg) ^ sw) << 2]);
    bf16x8 ah, al;
    CVT1(0, v0.x) CVT1(1, v0.y) CVT1(2, v0.z) CVT1(3, v0.w)
    CVT1(4, v1.x) CVT1(5, v1.y) CVT1(6, v1.z) CVT1(7, v1.w)
#pragma unroll
    for (int nt = 0; nt < 8; ++nt) {
      acc[nt] = __builtin_amdgcn_mfma_f32_16x16x32_bf16(ah, bh[nt], acc[nt], 0, 0, 0);
      acc[nt] = __builtin_amdgcn_mfma_f32_16x16x32_bf16(al, bh[nt], acc[nt], 0, 0, 0);
      acc[nt] = __builtin_amdgcn_mfma_f32_16x16x32_bf16(ah, bl[nt], acc[nt], 0, 0, 0);
    }
  }
}

// ---------------- fused RGCN layer ----------------

__launch_bounds__(256, 2)
__global__ void k_fused(const float* __restrict__ x,
                        const unsigned short* __restrict__ Wpk,
                        const float* __restrict__ Wb,
                        const int* __restrict__ srt, const int* __restrict__ off,
                        const float* __restrict__ deg, float* __restrict__ xo) {
  __shared__ float S[BR][D];             // 32,768 B (swizzled accumulation tile)
  __shared__ float G[GS][D];             // 47,104 B DMA staging
  __shared__ int dls[GS];
  const int nb = blockIdx.x;
  const int row0 = nb * BR;
  const int wave = threadIdx.x >> 6, lane = threadIdx.x & 63;
  const float2* __restrict__ x2 = reinterpret_cast<const float2*>(x);
  const bf16x8* __restrict__ Wf = reinterpret_cast<const bf16x8*>(Wpk);

  f32x4 acc[8];
#pragma unroll
  for (int nt = 0; nt < 8; ++nt) acc[nt] = 0.f;

  auto zeroS = [&]() {
    float4* S4 = reinterpret_cast<float4*>(&S[0][0]);
#pragma unroll
    for (int t = 0; t < 8; ++t)
      S4[threadIdx.x + 256 * t] = make_float4(0.f, 0.f, 0.f, 0.f);
  };
  auto issueDMA = [&](int b) {
    const int base = off[b], end = off[b + 1];
#pragma unroll
    for (int t = 0; t < PF; ++t) {
      int s = wave + 4 * t;
      int i = base + s;
      int p = (i < end) ? srt[i] : -1;
      if (lane == 0) dls[s] = p;
      if (p >= 0) {
        const float* row = x + (size_t)(p & 0xFFFF) * D;
        gl_lds4(row + lane, &G[s][0]);
        gl_lds4(row + 64 + lane, &G[s][64]);
      }
    }
  };
  auto depositE = [&](int b) {
#pragma unroll
    for (int t = 0; t < PF; ++t) {
      int s = wave + 4 * t;
      int p = dls[s];
      if (p >= 0) {
        float2 v = *reinterpret_cast<const float2*>(&G[s][2 * lane]);
        int dl = p >> 16;
        float* dst = &S[dl][(((lane >> 1) ^ (dl & 7)) << 2) + ((lane & 1) << 1)];
        atomicAdd(dst, v.x);
        atomicAdd(dst + 1, v.y);
      }
    }
    const int end = off[b + 1];            // overflow edges (bin > GS), rare
    for (int i = off[b] + GS + wave; i < end; i += 4) {
      int p = srt[i];
      float2 vv = x2[(size_t)(p & 0xFFFF) * 64 + lane];
      int dl = p >> 16;
      float* dst = &S[dl][(((lane >> 1) ^ (dl & 7)) << 2) + ((lane & 1) << 1)];
      atomicAdd(dst, vv.x);
      atomicAdd(dst + 1, vv.y);
    }
  };

  zeroS();
  issueDMA(nb * NR);
  __syncthreads();                         // zero + dls visible, DMA drained

  for (int r = 0; r < NR; ++r) {
    depositE(nb * NR + r);                 // LDS-only
    __syncthreads();                       // S complete for relation r
    if (r + 1 < NR) issueDMA(nb * NR + r + 1);
    mfma_rel(S, Wf + (size_t)r * 4096, lane, wave, acc);
    __syncthreads();                       // S reads done; DMAs drained
    if (r + 1 < NR) {
      zeroS();
      __syncthreads();
    }
  }

  // scale message aggregate by 1/deg (C rows: (lane>>4)*4 + j within mtile=wave)
  const int kg = lane >> 4;
#pragma unroll
  for (int j = 0; j < 4; ++j) {
    int row = row0 + wave * 16 + kg * 4 + j;
    float dv = (row < NN) ? deg[row] : 1.f;
    float inv = 1.f / fmaxf(dv, 1.f);
#pragma unroll
    for (int nt = 0; nt < 8; ++nt) acc[nt][j] *= inv;
  }

  // self phase: stage x rows into S (swizzled, full overwrite), then rel-16 MFMA
#pragma unroll
  for (int t = 0; t < 8; ++t) {
    int idx = threadIdx.x + 256 * t;
    int rw = idx >> 5, c = idx & 31;
    float4 vv = make_float4(0.f, 0.f, 0.f, 0.f);
    if (row0 + rw < NN)
      vv = reinterpret_cast<const float4*>(x)[(size_t)(row0 + rw) * 32 + c];
    *reinterpret_cast<float4*>(&S[rw][(c ^ (rw & 7)) << 2]) = vv;
  }
  __syncthreads();
  mfma_rel(S, Wf + (size_t)16 * 4096, lane, wave, acc);

  // epilogue: relu(acc + bias); C layout col = lane&15 + nt*16, row = kg*4+j
#pragma unroll
  for (int nt = 0; nt < 8; ++nt) {
    int col = nt * 16 + (lane & 15);
    float b = Wb[col];
#pragma unroll
    for (int j = 0; j < 4; ++j) {
      int row = row0 + wave * 16 + kg * 4 + j;
      if (row < NN)
        xo[(size_t)row * D + col] = fmaxf(acc[nt][j] + b, 0.f);
    }
  }
}

// ---------------- DistMult scoring ----------------

__global__ void k_score(const float* __restrict__ x, const float* __restrict__ rel,
                        const int* __restrict__ hh, const int* __restrict__ rr,
                        const int* __restrict__ tt, float* __restrict__ out) {
  int gw = (blockIdx.x * blockDim.x + threadIdx.x) >> 6;
  int lane = threadIdx.x & 63;
  int nw = (gridDim.x * blockDim.x) >> 6;
  for (int i = gw; i < NT; i += nw) {
    const float2* ph = reinterpret_cast<const float2*>(x + (size_t)hh[i] * D);
    const float2* pr = reinterpret_cast<const float2*>(rel + (size_t)rr[i] * D);
    const float2* pt = reinterpret_cast<const float2*>(x + (size_t)tt[i] * D);
    float2 a = ph[lane], b = pr[lane], c = pt[lane];
    float v = a.x * b.x * c.x + a.y * b.y * c.y;
#pragma unroll
    for (int m = 32; m; m >>= 1) v += __shfl_xor(v, m);
    if (lane == 0) out[i] = v;
  }
}

// ---------------- launch ----------------

extern "C" void kernel_launch(void* const* d_in, const int* in_sizes, int n_in,
                              void* d_out, int out_size, void* d_ws, size_t ws_size,
                              hipStream_t stream) {
  const float* node_emb = (const float*)d_in[0];
  const float* rel_emb  = (const float*)d_in[1];
  const float* W_rel0   = (const float*)d_in[2];
  const float* Wself_w0 = (const float*)d_in[3];
  const float* Wself_b0 = (const float*)d_in[4];
  const float* W_rel1   = (const float*)d_in[5];
  const float* Wself_w1 = (const float*)d_in[6];
  const float* Wself_b1 = (const float*)d_in[7];
  const int* local_nodes = (const int*)d_in[8];
  const int* edge_index  = (const int*)d_in[9];
  const int* edge_type   = (const int*)d_in[10];
  const int* h_loc = (const int*)d_in[11];
  const int* r_ids = (const int*)d_in[12];
  const int* t_loc = (const int*)d_in[13];
  float* out = (float*)d_out;

  // workspace layout (bytes)
  char* ws = (char*)d_ws;
  float* x_a = (float*)(ws + 0);                    // 15,360,000
  float* x_b = (float*)(ws + 15360000);             // 15,360,000
  float* deg = (float*)(ws + 30720000);             //    120,000
  int* bins  = (int*)(ws + 30840000);               //     30,016
  int* off   = (int*)(ws + 30870016);               //     30,020 (7505 ints)
  int* cur   = (int*)(ws + 30900036);               //     30,016
  int* srt   = (int*)(ws + 30930052);               //  1,920,000
  unsigned short* Wpk0 = (unsigned short*)(ws + 32850064);   // 1,114,112 (16B-aligned)
  unsigned short* Wpk1 = (unsigned short*)(ws + 33964176);   // 1,114,112
  if (ws_size < (size_t)35078288) return;

  // zero deg + bins (contiguous); off/cur/srt/Wpk fully overwritten downstream
  hipMemsetAsync(ws + 30720000, 0, 150016, stream);

  k_gather_x<<<3750, 256, 0, stream>>>(node_emb, local_nodes, x_a);
  k_hist_bins<<<1875, 256, 0, stream>>>(edge_index, edge_type, bins);
  k_scan_bins<<<1, 1024, 0, stream>>>(bins, off, cur);
  k_fill<<<1875, 256, 0, stream>>>(edge_index, edge_type, cur, srt, deg);
  k_packW<<<17, 256, 0, stream>>>(W_rel0, Wself_w0, Wpk0);
  k_packW<<<17, 256, 0, stream>>>(W_rel1, Wself_w1, Wpk1);

  k_fused<<<NBLK, 256, 0, stream>>>(x_a, Wpk0, Wself_b0, srt, off, deg, x_b);
  k_fused<<<NBLK, 256, 0, stream>>>(x_b, Wpk1, Wself_b1, srt, off, deg, x_a);

  k_score<<<1024, 256, 0, stream>>>(x_a, rel_emb, h_loc, r_ids, t_loc, out);
}